// Round 1
// baseline (7323.244 us; speedup 1.0000x reference)
//
#include <hip/hip_runtime.h>

// DeeperGCN on MI355X — round 1 baseline.
// Structure per GENConv: one fused edge pass (denom += exp(msg), num += msg*exp(msg);
// segment-max skipped — softmax is shift-invariant and values are bounded), then a
// per-node fused MLP (64->128->LN->relu->64) with W1/W2 in LDS (64KB) and shfl-based
// activation broadcast. graph-LN via f64-atomic global stats + fused apply. Head fully fused.

#define NN 100000
#define NE 800000
#define CH 64
#define NC (NN * CH)
#define HIDDEN 128
#define EPS_MSG 1e-7f
#define EPS_LN 1e-5f

// ---------------- edge aggregation pass ----------------
// thread layout: 16 threads per edge, each handles 4 consecutive channels (float4)
__global__ __launch_bounds__(256) void edge_kernel(
    const float* __restrict__ x, const int* __restrict__ ei,
    float* __restrict__ den, float* __restrict__ num)
{
    int idx = blockIdx.x * 256 + threadIdx.x;
    if (idx >= NE * 16) return;
    int e = idx >> 4;
    int c = (idx & 15) << 2;
    int src = ei[e];
    int dst = ei[NE + e];
    const float4 v = *reinterpret_cast<const float4*>(x + (size_t)src * CH + c);
    float m0 = fmaxf(v.x, 0.f) + EPS_MSG;
    float m1 = fmaxf(v.y, 0.f) + EPS_MSG;
    float m2 = fmaxf(v.z, 0.f) + EPS_MSG;
    float m3 = fmaxf(v.w, 0.f) + EPS_MSG;
    float e0 = expf(m0), e1 = expf(m1), e2 = expf(m2), e3 = expf(m3);
    float* dp = den + (size_t)dst * CH + c;
    float* np = num + (size_t)dst * CH + c;
    unsafeAtomicAdd(dp + 0, e0);
    unsafeAtomicAdd(dp + 1, e1);
    unsafeAtomicAdd(dp + 2, e2);
    unsafeAtomicAdd(dp + 3, e3);
    unsafeAtomicAdd(np + 0, m0 * e0);
    unsafeAtomicAdd(np + 1, m1 * e1);
    unsafeAtomicAdd(np + 2, m2 * e2);
    unsafeAtomicAdd(np + 3, m3 * e3);
}

// ---------------- per-node conv MLP ----------------
// one wave per node; lane l owns channel l (input/output) and hidden channels l, l+64.
// W1 [64x128], W2 [128x64] staged in LDS (exactly 64 KB). Activation broadcast via shfl.
template <int ACC>
__global__ __launch_bounds__(256) void conv_mlp_kernel(
    const float* __restrict__ xin, const float* __restrict__ num,
    const float* __restrict__ den,
    const float* __restrict__ W1, const float* __restrict__ b1,
    const float* __restrict__ lnw, const float* __restrict__ lnb,
    const float* __restrict__ W2, const float* __restrict__ b2,
    float* __restrict__ out)
{
    __shared__ float sW1[CH * HIDDEN];   // 32 KB
    __shared__ float sW2[HIDDEN * CH];   // 32 KB
    for (int i = threadIdx.x; i < CH * HIDDEN; i += 256) sW1[i] = W1[i];
    for (int i = threadIdx.x; i < HIDDEN * CH; i += 256) sW2[i] = W2[i];
    __syncthreads();

    const int lane = threadIdx.x & 63;
    const int wv = threadIdx.x >> 6;
    const float b1a = b1[lane], b1b = b1[lane + 64];
    const float ga = lnw[lane], gb = lnw[lane + 64];
    const float ba = lnb[lane], bb = lnb[lane + 64];
    const float b2v = b2[lane];

    int w = blockIdx.x * 4 + wv;
    int nwaves = gridDim.x * 4;
    for (int n = w; n < NN; n += nwaves) {
        size_t base = (size_t)n * CH + lane;
        float d = den[base], u = num[base];
        float agg = d > 0.f ? u / d : 0.f;   // no-incoming-edge nodes -> 0
        float h = agg + xin[base];

        float h1a = b1a, h1b = b1b;
        #pragma unroll 8
        for (int k = 0; k < 64; ++k) {
            float xk = __shfl(h, k);
            h1a = fmaf(xk, sW1[k * HIDDEN + lane], h1a);
            h1b = fmaf(xk, sW1[k * HIDDEN + lane + 64], h1b);
        }
        // LayerNorm over 128 hidden features (2 per lane)
        float s = h1a + h1b;
        float sq = fmaf(h1a, h1a, h1b * h1b);
        #pragma unroll
        for (int off = 32; off; off >>= 1) {
            s += __shfl_xor(s, off);
            sq += __shfl_xor(sq, off);
        }
        float mu = s * (1.f / HIDDEN);
        float var = sq * (1.f / HIDDEN) - mu * mu;
        float rstd = 1.f / sqrtf(var + EPS_LN);
        float r0 = fmaxf(fmaf((h1a - mu) * rstd, ga, ba), 0.f);
        float r1 = fmaxf(fmaf((h1b - mu) * rstd, gb, bb), 0.f);

        float o = b2v;
        #pragma unroll 8
        for (int k = 0; k < 64; ++k) {
            float ra = __shfl(r0, k);
            float rb = __shfl(r1, k);
            o = fmaf(ra, sW2[k * CH + lane], o);
            o = fmaf(rb, sW2[(k + 64) * CH + lane], o);
        }
        if (ACC) out[base] += o; else out[base] = o;
    }
}

// ---------------- graph-LN stats ----------------
__global__ __launch_bounds__(256) void ln_stats_kernel(
    const float* __restrict__ a, double* __restrict__ dsum)
{
    float s = 0.f, sq = 0.f;
    int idx = blockIdx.x * 256 + threadIdx.x;
    int stride = gridDim.x * 256;
    for (int i = idx; i < NC / 4; i += stride) {
        float4 v = reinterpret_cast<const float4*>(a)[i];
        s += (v.x + v.y) + (v.z + v.w);
        sq += fmaf(v.x, v.x, v.y * v.y) + fmaf(v.z, v.z, v.w * v.w);
    }
    #pragma unroll
    for (int off = 32; off; off >>= 1) {
        s += __shfl_down(s, off);
        sq += __shfl_down(sq, off);
    }
    __shared__ float ps[4], pq[4];
    int lane = threadIdx.x & 63, wv = threadIdx.x >> 6;
    if (lane == 0) { ps[wv] = s; pq[wv] = sq; }
    __syncthreads();
    if (threadIdx.x == 0) {
        unsafeAtomicAdd(dsum + 0, (double)((ps[0] + ps[1]) + (ps[2] + ps[3])));
        unsafeAtomicAdd(dsum + 1, (double)((pq[0] + pq[1]) + (pq[2] + pq[3])));
    }
}

// ---------------- graph-LN apply (+relu) ----------------
__global__ __launch_bounds__(256) void ln_apply_kernel(
    const float* __restrict__ in, const float* __restrict__ w,
    const float* __restrict__ b, const double* __restrict__ dsum,
    float* __restrict__ out)
{
    int idx = blockIdx.x * 256 + threadIdx.x;
    if (idx >= NC / 4) return;
    double S = dsum[0], Q = dsum[1];
    double mud = S / (double)NC;
    float mu = (float)mud;
    float var = (float)(Q / (double)NC - mud * mud);
    float scale = 1.f / (sqrtf(fmaxf(var, 0.f)) + EPS_LN);   // /(std+eps), std=sqrt(biased var)
    int c = (idx & 15) << 2;
    float4 v = reinterpret_cast<const float4*>(in)[idx];
    float4 wv = *reinterpret_cast<const float4*>(w + c);
    float4 bv = *reinterpret_cast<const float4*>(b + c);
    float4 o;
    o.x = fmaxf(fmaf((v.x - mu) * scale, wv.x, bv.x), 0.f);
    o.y = fmaxf(fmaf((v.y - mu) * scale, wv.y, bv.y), 0.f);
    o.z = fmaxf(fmaf((v.z - mu) * scale, wv.z, bv.z), 0.f);
    o.w = fmaxf(fmaf((v.w - mu) * scale, wv.w, bv.w), 0.f);
    reinterpret_cast<float4*>(out)[idx] = o;
}

// ---------------- fused MLP head: 64 -> relu 64 -> relu 64 -> 2 ----------------
__global__ __launch_bounds__(256) void head_kernel(
    const float* __restrict__ xc,
    const float* __restrict__ W1, const float* __restrict__ b1,
    const float* __restrict__ W2, const float* __restrict__ b2,
    const float* __restrict__ W3, const float* __restrict__ b3,
    float* __restrict__ out)
{
    __shared__ float sW1[64 * 64], sW2[64 * 64];   // 32 KB
    for (int i = threadIdx.x; i < 64 * 64; i += 256) { sW1[i] = W1[i]; sW2[i] = W2[i]; }
    __syncthreads();
    int lane = threadIdx.x & 63, wv = threadIdx.x >> 6;
    float b1v = b1[lane], b2v = b2[lane];
    float w30 = W3[lane * 2], w31 = W3[lane * 2 + 1];
    float b30 = b3[0], b31 = b3[1];
    int w = blockIdx.x * 4 + wv, nwaves = gridDim.x * 4;
    for (int n = w; n < NN; n += nwaves) {
        float xv = xc[(size_t)n * 64 + lane];
        float y1 = b1v;
        #pragma unroll 8
        for (int k = 0; k < 64; ++k) y1 = fmaf(__shfl(xv, k), sW1[k * 64 + lane], y1);
        y1 = fmaxf(y1, 0.f);
        float y2 = b2v;
        #pragma unroll 8
        for (int k = 0; k < 64; ++k) y2 = fmaf(__shfl(y1, k), sW2[k * 64 + lane], y2);
        y2 = fmaxf(y2, 0.f);
        float p0 = y2 * w30, p1 = y2 * w31;
        #pragma unroll
        for (int off = 32; off; off >>= 1) {
            p0 += __shfl_xor(p0, off);
            p1 += __shfl_xor(p1, off);
        }
        if (lane == 0) {
            out[(size_t)n * 2 + 0] = p0 + b30;
            out[(size_t)n * 2 + 1] = p1 + b31;
        }
    }
}

extern "C" void kernel_launch(void* const* d_in, const int* in_sizes, int n_in,
                              void* d_out, int out_size, void* d_ws, size_t ws_size,
                              hipStream_t stream)
{
    const float* x     = (const float*)d_in[0];
    const int*   ei    = (const int*)d_in[1];
    const float* c1W1  = (const float*)d_in[2];
    const float* c1b1  = (const float*)d_in[3];
    const float* c1lnw = (const float*)d_in[4];
    const float* c1lnb = (const float*)d_in[5];
    const float* c1W2  = (const float*)d_in[6];
    const float* c1b2  = (const float*)d_in[7];
    const float* n1w   = (const float*)d_in[8];
    const float* n1b   = (const float*)d_in[9];
    const float* cW1   = (const float*)d_in[10];
    const float* cb1   = (const float*)d_in[11];
    const float* clnw  = (const float*)d_in[12];
    const float* clnb  = (const float*)d_in[13];
    const float* cW2   = (const float*)d_in[14];
    const float* cb2   = (const float*)d_in[15];
    const float* nw    = (const float*)d_in[16];
    const float* nb    = (const float*)d_in[17];
    const float* lW1   = (const float*)d_in[18];
    const float* lb1   = (const float*)d_in[19];
    const float* lW2   = (const float*)d_in[20];
    const float* lb2   = (const float*)d_in[21];
    const float* lW3   = (const float*)d_in[22];
    const float* lb3   = (const float*)d_in[23];
    float* out = (float*)d_out;

    // workspace layout: 5 x [N,64] f32 buffers + 2 doubles  (~128 MB)
    float* xc  = (float*)d_ws;
    float* xl  = xc + NC;
    float* tmp = xl + NC;
    float* den = tmp + NC;
    float* num = den + NC;   // den,num contiguous -> single memset
    double* dsum = (double*)(num + NC);

    const int EDGE_BLOCKS  = (NE * 16) / 256;      // 50000
    const int APPLY_BLOCKS = (NC / 4 + 255) / 256; // 6250

    auto conv = [&](const float* xin, const float* W1p, const float* b1p,
                    const float* lnwp, const float* lnbp,
                    const float* W2p, const float* b2p, float* o, bool acc) {
        hipMemsetAsync(den, 0, (size_t)2 * NC * sizeof(float), stream);
        edge_kernel<<<EDGE_BLOCKS, 256, 0, stream>>>(xin, ei, den, num);
        if (acc)
            conv_mlp_kernel<1><<<512, 256, 0, stream>>>(xin, num, den, W1p, b1p, lnwp, lnbp, W2p, b2p, o);
        else
            conv_mlp_kernel<0><<<512, 256, 0, stream>>>(xin, num, den, W1p, b1p, lnwp, lnbp, W2p, b2p, o);
    };
    auto gln = [&](const float* in, const float* wp, const float* bp, float* o) {
        hipMemsetAsync(dsum, 0, 2 * sizeof(double), stream);
        ln_stats_kernel<<<2048, 256, 0, stream>>>(in, dsum);
        ln_apply_kernel<<<APPLY_BLOCKS, 256, 0, stream>>>(in, wp, bp, dsum, o);
    };

    // layer 1 (plain): conv -> graph_ln -> relu
    conv(x, c1W1, c1b1, c1lnw, c1lnb, c1W2, c1b2, tmp, false);
    gln(tmp, n1w, n1b, xc);

    // layers 2..4 (res+): norm -> act -> conv -> residual add
    for (int i = 0; i < 3; ++i) {
        gln(xc, nw + i * 64, nb + i * 64, xl);
        conv(xl, cW1 + i * 64 * 128, cb1 + i * 128, clnw + i * 128, clnb + i * 128,
             cW2 + i * 128 * 64, cb2 + i * 64, xc, true);
    }

    // dense head
    head_kernel<<<256, 256, 0, stream>>>(xc, lW1, lb1, lW2, lb2, lW3, lb3, out);
}

// Round 2
// 2083.571 us; speedup vs baseline: 3.5148x; 3.5148x over previous
//
#include <hip/hip_runtime.h>

// DeeperGCN round 2 — atomic-free aggregation via per-launch counting sort (CSR by dst),
// fully fused conv (gather+softmax-agg+MLP) one-wave-per-node, graph-LN folded into
// consumers via running (sum,sumsq) f64 slots. Ping-pong buffers for res+ layers.

#define NN 100000
#define NE 800000
#define CH 64
#define NC (NN * CH)
#define HIDDEN 128
#define EPS_MSG 1e-7f
#define EPS_LN 1e-5f

// ---------------- counting sort: histogram ----------------
__global__ __launch_bounds__(256) void hist_kernel(const int* __restrict__ ei,
                                                   int* __restrict__ cursor) {
    int e = blockIdx.x * 256 + threadIdx.x;
    if (e < NE) atomicAdd(&cursor[ei[NE + e]], 1);
}

// ---------------- single-block scan: cursor(deg) -> off (row ptrs), cursor = starts ----------------
__global__ __launch_bounds__(1024) void scan_kernel(int* __restrict__ cursor,
                                                    int* __restrict__ off) {
    __shared__ int sc[1024];
    const int t = threadIdx.x;
    const int base = t * 98;            // 1024*98 = 100352 >= NN
    int s = 0;
    for (int j = 0; j < 98; ++j) { int i = base + j; if (i < NN) s += cursor[i]; }
    sc[t] = s;
    __syncthreads();
    for (int o = 1; o < 1024; o <<= 1) {
        int v = (t >= o) ? sc[t - o] : 0;
        __syncthreads();
        sc[t] += v;
        __syncthreads();
    }
    int run = sc[t] - s;                // exclusive prefix for this thread's chunk
    for (int j = 0; j < 98; ++j) {
        int i = base + j;
        if (i < NN) { int d = cursor[i]; off[i] = run; cursor[i] = run; run += d; }
    }
    if (t == 0) off[NN] = NE;
}

// ---------------- scatter src ids grouped by dst ----------------
__global__ __launch_bounds__(256) void scatter_kernel(const int* __restrict__ ei,
                                                      int* __restrict__ cursor,
                                                      int* __restrict__ esrc) {
    int e = blockIdx.x * 256 + threadIdx.x;
    if (e >= NE) return;
    int dst = ei[NE + e];
    int pos = atomicAdd(&cursor[dst], 1);
    esrc[pos] = ei[e];
}

// ---------------- fused GENConv ----------------
// MODE 0: plain layer (input raw, out = mlp(agg + x))
// MODE 1: res+ layer (on-the-fly relu(graph_ln(.)) via ds_in scalars, out = x + mlp(...))
// Both accumulate stats(out) -> ds_out. One wave per node, lane = channel.
template <int MODE>
__global__ __launch_bounds__(512) void conv_kernel(
    const float* __restrict__ xin, const int* __restrict__ off,
    const int* __restrict__ esrc, const double* __restrict__ ds_in,
    const float* __restrict__ gw, const float* __restrict__ gbp,
    const float* __restrict__ W1, const float* __restrict__ b1,
    const float* __restrict__ lnw, const float* __restrict__ lnb,
    const float* __restrict__ W2, const float* __restrict__ b2,
    float* __restrict__ out, double* __restrict__ ds_out)
{
    __shared__ float sW1[CH * HIDDEN];   // 32 KB
    __shared__ float sW2[HIDDEN * CH];   // 32 KB
    __shared__ float ps[8], pq[8];
    for (int i = threadIdx.x; i < CH * HIDDEN; i += 512) sW1[i] = W1[i];
    for (int i = threadIdx.x; i < HIDDEN * CH; i += 512) sW2[i] = W2[i];
    __syncthreads();

    const int lane = threadIdx.x & 63;
    const int wv = threadIdx.x >> 6;

    float A = 1.f, B = 0.f;
    if (MODE == 1) {
        double S = ds_in[0], Q = ds_in[1];
        double mud = S / (double)NC;
        float var = (float)(Q / (double)NC - mud * mud);
        float scale = 1.f / (sqrtf(fmaxf(var, 0.f)) + EPS_LN);
        A = scale * gw[lane];
        B = fmaf(-(float)mud, A, gbp[lane]);
    }
    const float b1a = b1[lane], b1b = b1[lane + 64];
    const float ga = lnw[lane], gb2 = lnw[lane + 64];
    const float ba = lnb[lane], bb = lnb[lane + 64];
    const float b2v = b2[lane];

    float acc_s = 0.f, acc_q = 0.f;
    const int w0 = blockIdx.x * 8 + wv, nw = gridDim.x * 8;
    for (int n = w0; n < NN; n += nw) {
        const size_t base = (size_t)n * CH + lane;
        const float xb = xin[base];
        int p = off[n];
        const int p1 = off[n + 1];
        float den = 0.f, num = 0.f;
        if (p < p1) {
            float v = xin[(size_t)esrc[p] * CH + lane];   // prefetch-1 pipeline
            while (++p < p1) {
                float vn = xin[(size_t)esrc[p] * CH + lane];
                float m = MODE ? fmaxf(fmaf(v, A, B), 0.f) + EPS_MSG
                               : fmaxf(v, 0.f) + EPS_MSG;
                float e = __expf(m);
                den += e; num = fmaf(m, e, num);
                v = vn;
            }
            float m = MODE ? fmaxf(fmaf(v, A, B), 0.f) + EPS_MSG
                           : fmaxf(v, 0.f) + EPS_MSG;
            float e = __expf(m);
            den += e; num = fmaf(m, e, num);
        }
        float agg = den > 0.f ? num / den : 0.f;   // deg==0 -> 0 (matches segment_sum on empty)
        float xl = MODE ? fmaxf(fmaf(xb, A, B), 0.f) : xb;
        float h = agg + xl;

        // MLP: 64 -> 128 -> LN -> relu -> 64
        float h1a = b1a, h1b = b1b;
        #pragma unroll 8
        for (int k = 0; k < 64; ++k) {
            float xk = __shfl(h, k);
            h1a = fmaf(xk, sW1[k * HIDDEN + lane], h1a);
            h1b = fmaf(xk, sW1[k * HIDDEN + lane + 64], h1b);
        }
        float s = h1a + h1b;
        float sq = fmaf(h1a, h1a, h1b * h1b);
        #pragma unroll
        for (int o = 32; o; o >>= 1) { s += __shfl_xor(s, o); sq += __shfl_xor(sq, o); }
        float mu = s * (1.f / HIDDEN);
        float var = sq * (1.f / HIDDEN) - mu * mu;
        float rstd = 1.f / sqrtf(var + EPS_LN);
        float r0 = fmaxf(fmaf((h1a - mu) * rstd, ga, ba), 0.f);
        float r1 = fmaxf(fmaf((h1b - mu) * rstd, gb2, bb), 0.f);
        float o2 = b2v;
        #pragma unroll 8
        for (int k = 0; k < 64; ++k) {
            float ra = __shfl(r0, k);
            float rb = __shfl(r1, k);
            o2 = fmaf(ra, sW2[k * CH + lane], o2);
            o2 = fmaf(rb, sW2[(k + 64) * CH + lane], o2);
        }
        float val = MODE ? xb + o2 : o2;
        out[base] = val;
        acc_s += val;
        acc_q = fmaf(val, val, acc_q);
    }
    #pragma unroll
    for (int o = 32; o; o >>= 1) { acc_s += __shfl_xor(acc_s, o); acc_q += __shfl_xor(acc_q, o); }
    if (lane == 0) { ps[wv] = acc_s; pq[wv] = acc_q; }
    __syncthreads();
    if (threadIdx.x == 0) {
        float ts = 0.f, tq = 0.f;
        #pragma unroll
        for (int i = 0; i < 8; ++i) { ts += ps[i]; tq += pq[i]; }
        unsafeAtomicAdd(ds_out + 0, (double)ts);
        unsafeAtomicAdd(ds_out + 1, (double)tq);
    }
}

// ---------------- layer-1 graph-LN apply (+relu) with output stats ----------------
__global__ __launch_bounds__(256) void ln_apply_kernel(
    const float* __restrict__ in, const float* __restrict__ w,
    const float* __restrict__ b, const double* __restrict__ ds_in,
    float* __restrict__ out, double* __restrict__ ds_out)
{
    __shared__ float ps[4], pq[4];
    double S = ds_in[0], Q = ds_in[1];
    double mud = S / (double)NC;
    float mu = (float)mud;
    float var = (float)(Q / (double)NC - mud * mud);
    float scale = 1.f / (sqrtf(fmaxf(var, 0.f)) + EPS_LN);
    float s = 0.f, q = 0.f;
    int idx = blockIdx.x * 256 + threadIdx.x;
    int stride = gridDim.x * 256;
    for (int i = idx; i < NC / 4; i += stride) {
        int c = (i & 15) << 2;
        float4 v = reinterpret_cast<const float4*>(in)[i];
        float4 wv = *reinterpret_cast<const float4*>(w + c);
        float4 bv = *reinterpret_cast<const float4*>(b + c);
        float4 o;
        o.x = fmaxf(fmaf((v.x - mu) * scale, wv.x, bv.x), 0.f);
        o.y = fmaxf(fmaf((v.y - mu) * scale, wv.y, bv.y), 0.f);
        o.z = fmaxf(fmaf((v.z - mu) * scale, wv.z, bv.z), 0.f);
        o.w = fmaxf(fmaf((v.w - mu) * scale, wv.w, bv.w), 0.f);
        reinterpret_cast<float4*>(out)[i] = o;
        s += (o.x + o.y) + (o.z + o.w);
        q += fmaf(o.x, o.x, o.y * o.y) + fmaf(o.z, o.z, o.w * o.w);
    }
    int lane = threadIdx.x & 63, wv2 = threadIdx.x >> 6;
    #pragma unroll
    for (int o = 32; o; o >>= 1) { s += __shfl_xor(s, o); q += __shfl_xor(q, o); }
    if (lane == 0) { ps[wv2] = s; pq[wv2] = q; }
    __syncthreads();
    if (threadIdx.x == 0) {
        unsafeAtomicAdd(ds_out + 0, (double)((ps[0] + ps[1]) + (ps[2] + ps[3])));
        unsafeAtomicAdd(ds_out + 1, (double)((pq[0] + pq[1]) + (pq[2] + pq[3])));
    }
}

// ---------------- fused MLP head: 64 -> relu 64 -> relu 64 -> 2 ----------------
__global__ __launch_bounds__(256) void head_kernel(
    const float* __restrict__ xc,
    const float* __restrict__ W1, const float* __restrict__ b1,
    const float* __restrict__ W2, const float* __restrict__ b2,
    const float* __restrict__ W3, const float* __restrict__ b3,
    float* __restrict__ out)
{
    __shared__ float sW1[64 * 64], sW2[64 * 64];
    for (int i = threadIdx.x; i < 64 * 64; i += 256) { sW1[i] = W1[i]; sW2[i] = W2[i]; }
    __syncthreads();
    int lane = threadIdx.x & 63, wv = threadIdx.x >> 6;
    float b1v = b1[lane], b2v = b2[lane];
    float w30 = W3[lane * 2], w31 = W3[lane * 2 + 1];
    float b30 = b3[0], b31 = b3[1];
    int w = blockIdx.x * 4 + wv, nwaves = gridDim.x * 4;
    for (int n = w; n < NN; n += nwaves) {
        float xv = xc[(size_t)n * 64 + lane];
        float y1 = b1v;
        #pragma unroll 8
        for (int k = 0; k < 64; ++k) y1 = fmaf(__shfl(xv, k), sW1[k * 64 + lane], y1);
        y1 = fmaxf(y1, 0.f);
        float y2 = b2v;
        #pragma unroll 8
        for (int k = 0; k < 64; ++k) y2 = fmaf(__shfl(y1, k), sW2[k * 64 + lane], y2);
        y2 = fmaxf(y2, 0.f);
        float p0 = y2 * w30, p1 = y2 * w31;
        #pragma unroll
        for (int off = 32; off; off >>= 1) {
            p0 += __shfl_xor(p0, off);
            p1 += __shfl_xor(p1, off);
        }
        if (lane == 0) {
            out[(size_t)n * 2 + 0] = p0 + b30;
            out[(size_t)n * 2 + 1] = p1 + b31;
        }
    }
}

extern "C" void kernel_launch(void* const* d_in, const int* in_sizes, int n_in,
                              void* d_out, int out_size, void* d_ws, size_t ws_size,
                              hipStream_t stream)
{
    const float* x     = (const float*)d_in[0];
    const int*   ei    = (const int*)d_in[1];
    const float* c1W1  = (const float*)d_in[2];
    const float* c1b1  = (const float*)d_in[3];
    const float* c1lnw = (const float*)d_in[4];
    const float* c1lnb = (const float*)d_in[5];
    const float* c1W2  = (const float*)d_in[6];
    const float* c1b2  = (const float*)d_in[7];
    const float* n1w   = (const float*)d_in[8];
    const float* n1b   = (const float*)d_in[9];
    const float* cW1   = (const float*)d_in[10];
    const float* cb1   = (const float*)d_in[11];
    const float* clnw  = (const float*)d_in[12];
    const float* clnb  = (const float*)d_in[13];
    const float* cW2   = (const float*)d_in[14];
    const float* cb2   = (const float*)d_in[15];
    const float* nw    = (const float*)d_in[16];
    const float* nb    = (const float*)d_in[17];
    const float* lW1   = (const float*)d_in[18];
    const float* lb1   = (const float*)d_in[19];
    const float* lW2   = (const float*)d_in[20];
    const float* lb2   = (const float*)d_in[21];
    const float* lW3   = (const float*)d_in[22];
    const float* lb3   = (const float*)d_in[23];
    float* out = (float*)d_out;

    // workspace: bufA, bufB [N,64] f32; cursor[NN]; off[NN+2]; esrc[NE]; dsum[10] f64
    float* bufA = (float*)d_ws;
    float* bufB = bufA + NC;
    int* cursor = (int*)(bufB + NC);
    int* off    = cursor + NN;
    int* esrc   = off + NN + 2;
    double* dsum = (double*)(esrc + NE);   // 51.2e6 + 4.0e6 bytes, both 8B-aligned

    // build CSR (by dst) once; reused by all 4 convs
    hipMemsetAsync(cursor, 0, NN * sizeof(int), stream);
    hipMemsetAsync(dsum, 0, 10 * sizeof(double), stream);
    hist_kernel<<<3125, 256, 0, stream>>>(ei, cursor);
    scan_kernel<<<1, 1024, 0, stream>>>(cursor, off);
    scatter_kernel<<<3125, 256, 0, stream>>>(ei, cursor, esrc);

    // layer 1 (plain): conv(x) -> bufA (+stats ds0); gln+relu -> bufB (+stats ds1)
    conv_kernel<0><<<512, 512, 0, stream>>>(x, off, esrc, nullptr, nullptr, nullptr,
                                            c1W1, c1b1, c1lnw, c1lnb, c1W2, c1b2,
                                            bufA, dsum + 0);
    ln_apply_kernel<<<2048, 256, 0, stream>>>(bufA, n1w, n1b, dsum + 0, bufB, dsum + 2);

    // layers 2..4 (res+): xc_new = xc + mlp(agg(relu(gln(xc))) ...), ping-pong buffers
    conv_kernel<1><<<512, 512, 0, stream>>>(bufB, off, esrc, dsum + 2, nw + 0, nb + 0,
                                            cW1 + 0 * 8192, cb1 + 0 * 128, clnw + 0 * 128, clnb + 0 * 128,
                                            cW2 + 0 * 8192, cb2 + 0 * 64, bufA, dsum + 4);
    conv_kernel<1><<<512, 512, 0, stream>>>(bufA, off, esrc, dsum + 4, nw + 64, nb + 64,
                                            cW1 + 1 * 8192, cb1 + 1 * 128, clnw + 1 * 128, clnb + 1 * 128,
                                            cW2 + 1 * 8192, cb2 + 1 * 64, bufB, dsum + 6);
    conv_kernel<1><<<512, 512, 0, stream>>>(bufB, off, esrc, dsum + 6, nw + 128, nb + 128,
                                            cW1 + 2 * 8192, cb1 + 2 * 128, clnw + 2 * 128, clnb + 2 * 128,
                                            cW2 + 2 * 8192, cb2 + 2 * 64, bufA, dsum + 8);

    // dense head
    head_kernel<<<256, 256, 0, stream>>>(bufA, lW1, lb1, lW2, lb2, lW3, lb3, out);
}

// Round 3
// 1433.954 us; speedup vs baseline: 5.1070x; 1.4530x over previous
//
#include <hip/hip_runtime.h>

// DeeperGCN round 3 — split conv into agg (gather, no LDS, max TLP) + mlp
// (node-per-lane: weights via wave-uniform scalar loads, activations in registers,
// zero shuffles, LDS only for the 64x64 output transpose). Theory: round-2 conv was
// LDS-pipe throughput bound (~460 LDS ops/node: weight ds_reads + shfl bpermutes).

#define NN 100000
#define NE 800000
#define CH 64
#define NC (NN * CH)
#define NT 1563            // ceil(100000 / 64) node tiles
#define EPS_MSG 1e-7f
#define EPS_LN 1e-5f

// ---------------- counting sort: histogram ----------------
__global__ __launch_bounds__(256) void hist_kernel(const int* __restrict__ ei,
                                                   int* __restrict__ cursor) {
    int e = blockIdx.x * 256 + threadIdx.x;
    if (e < NE) atomicAdd(&cursor[ei[NE + e]], 1);
}

// ---------------- single-block scan ----------------
__global__ __launch_bounds__(1024) void scan_kernel(int* __restrict__ cursor,
                                                    int* __restrict__ off) {
    __shared__ int sc[1024];
    const int t = threadIdx.x;
    const int base = t * 98;
    int s = 0;
    for (int j = 0; j < 98; ++j) { int i = base + j; if (i < NN) s += cursor[i]; }
    sc[t] = s;
    __syncthreads();
    for (int o = 1; o < 1024; o <<= 1) {
        int v = (t >= o) ? sc[t - o] : 0;
        __syncthreads();
        sc[t] += v;
        __syncthreads();
    }
    int run = sc[t] - s;
    for (int j = 0; j < 98; ++j) {
        int i = base + j;
        if (i < NN) { int d = cursor[i]; off[i] = run; cursor[i] = run; run += d; }
    }
    if (t == 0) off[NN] = NE;
}

// ---------------- scatter src ids grouped by dst ----------------
__global__ __launch_bounds__(256) void scatter_kernel(const int* __restrict__ ei,
                                                      int* __restrict__ cursor,
                                                      int* __restrict__ esrc) {
    int e = blockIdx.x * 256 + threadIdx.x;
    if (e >= NE) return;
    int dst = ei[NE + e];
    int pos = atomicAdd(&cursor[dst], 1);
    esrc[pos] = ei[e];
}

// ---------------- aggregation: wave per node, channel per lane ----------------
// MODE 0: h = agg(relu(x_src)) + x   MODE 1: input passed through relu(graph_ln(.))
template <int MODE>
__global__ __launch_bounds__(256) void agg_kernel(
    const float* __restrict__ xin, const int* __restrict__ off,
    const int* __restrict__ esrc, const double* __restrict__ ds_in,
    const float* __restrict__ gw, const float* __restrict__ gb,
    float* __restrict__ hbuf)
{
    const int lane = threadIdx.x & 63;
    const int n = (blockIdx.x * 256 + threadIdx.x) >> 6;
    if (n >= NN) return;
    float A = 1.f, B = 0.f;
    if (MODE) {
        double S = ds_in[0], Q = ds_in[1];
        double mud = S / (double)NC;
        float var = (float)(Q / (double)NC - mud * mud);
        float scale = 1.f / (sqrtf(fmaxf(var, 0.f)) + EPS_LN);
        A = scale * gw[lane];
        B = fmaf(-(float)mud, A, gb[lane]);
    }
    const size_t base = (size_t)n * CH + lane;
    const float xb = xin[base];
    const int p0 = off[n], p1 = off[n + 1];
    float den = 0.f, num = 0.f;
    for (int q = p0; q < p1; q += 8) {          // 8-deep load pipeline per chunk
        int m = p1 - q; if (m > 8) m = 8;
        float v[8];
        #pragma unroll
        for (int i = 0; i < 8; ++i)
            if (i < m) v[i] = xin[(size_t)esrc[q + i] * CH + lane];
        #pragma unroll
        for (int i = 0; i < 8; ++i)
            if (i < m) {
                float mm = MODE ? fmaxf(fmaf(v[i], A, B), 0.f) + EPS_MSG
                                : fmaxf(v[i], 0.f) + EPS_MSG;
                float e = __expf(mm);
                den += e;
                num = fmaf(mm, e, num);
            }
    }
    float agg = den > 0.f ? num / den : 0.f;
    float xl = MODE ? fmaxf(fmaf(xb, A, B), 0.f) : xb;
    hbuf[base] = agg + xl;
}

// ---------------- MLP: node-per-lane, 64-node tile per wave ----------------
// 64 -> 128 -> torchLN -> relu -> 64. Weights via wave-uniform (scalar) loads.
// Hidden computed in 16-chunks; recomputed for layer 2 (bitwise-identical order).
// MODE 1 adds residual xres. Accumulates (sum, sumsq) of output -> ds_out.
template <int MODE>
__global__ __launch_bounds__(256) void mlp_kernel(
    const float* __restrict__ hbuf, const float* __restrict__ xres,
    const float* __restrict__ W1, const float* __restrict__ b1,
    const float* __restrict__ lnw, const float* __restrict__ lnb,
    const float* __restrict__ W2, const float* __restrict__ b2,
    float* __restrict__ out, double* __restrict__ ds_out)
{
    __shared__ float ot[4][64 * 65];            // per-wave output transpose tile
    const int lane = threadIdx.x & 63;
    const int wv = threadIdx.x >> 6;
    const int tile = blockIdx.x * 4 + wv;
    if (tile >= NT) return;                     // no barriers below: safe
    const int base = tile * 64;
    const int nvalid = (NN - base < 64) ? (NN - base) : 64;
    const int node = base + lane;
    const bool act = lane < nvalid;

    // transposed load: lane = node, x[c] in registers (strided float4, L1-resident)
    const float* xp = hbuf + (size_t)(act ? node : base) * CH;
    float x[64];
    #pragma unroll
    for (int c4 = 0; c4 < 16; ++c4) {
        float4 v = *reinterpret_cast<const float4*>(xp + c4 * 4);
        x[c4 * 4 + 0] = v.x; x[c4 * 4 + 1] = v.y;
        x[c4 * 4 + 2] = v.z; x[c4 * 4 + 3] = v.w;
    }

    // phase 1: hidden stats (chunks of 16, discard values)
    float s = 0.f, sq = 0.f;
    for (int jb = 0; jb < 8; ++jb) {
        float acc[16];
        #pragma unroll
        for (int i = 0; i < 16; ++i) acc[i] = b1[jb * 16 + i];
        #pragma unroll
        for (int c = 0; c < 64; ++c) {
            float xv = x[c];
            #pragma unroll
            for (int i = 0; i < 16; ++i)
                acc[i] = fmaf(xv, W1[c * 128 + jb * 16 + i], acc[i]);
        }
        #pragma unroll
        for (int i = 0; i < 16; ++i) { s += acc[i]; sq = fmaf(acc[i], acc[i], sq); }
    }
    const float mu = s * (1.f / 128.f);
    const float var = sq * (1.f / 128.f) - mu * mu;
    const float rstd = 1.f / sqrtf(var + EPS_LN);
    const float nmr = -mu * rstd;

    // phase 2: recompute hidden chunks, normalize+relu, accumulate layer 2
    float o2[64];
    #pragma unroll
    for (int c = 0; c < 64; ++c) o2[c] = b2[c];
    for (int jb = 0; jb < 8; ++jb) {
        float acc[16];
        #pragma unroll
        for (int i = 0; i < 16; ++i) acc[i] = b1[jb * 16 + i];
        #pragma unroll
        for (int c = 0; c < 64; ++c) {
            float xv = x[c];
            #pragma unroll
            for (int i = 0; i < 16; ++i)
                acc[i] = fmaf(xv, W1[c * 128 + jb * 16 + i], acc[i]);
        }
        #pragma unroll
        for (int i = 0; i < 16; ++i) {
            const int j = jb * 16 + i;
            float r = fmaxf(fmaf(fmaf(acc[i], rstd, nmr), lnw[j], lnb[j]), 0.f);
            #pragma unroll
            for (int c = 0; c < 64; ++c)
                o2[c] = fmaf(r, W2[j * 64 + c], o2[c]);
        }
    }

    // phase 3: transpose back through LDS, residual add, store, stats
    float* op = ot[wv];
    #pragma unroll
    for (int c = 0; c < 64; ++c) op[lane * 65 + c] = o2[c];
    float as = 0.f, aq = 0.f;
    #pragma unroll
    for (int r = 0; r < 64; ++r) {
        if (r < nvalid) {
            float val = op[r * 65 + lane];
            if (MODE) val += xres[(size_t)(base + r) * CH + lane];
            out[(size_t)(base + r) * CH + lane] = val;
            as += val;
            aq = fmaf(val, val, aq);
        }
    }
    #pragma unroll
    for (int o = 32; o; o >>= 1) { as += __shfl_xor(as, o); aq += __shfl_xor(aq, o); }
    if (lane == 0) {
        unsafeAtomicAdd(ds_out + 0, (double)as);
        unsafeAtomicAdd(ds_out + 1, (double)aq);
    }
}

// ---------------- layer-1 graph-LN apply (+relu) with output stats ----------------
__global__ __launch_bounds__(256) void ln_apply_kernel(
    const float* __restrict__ in, const float* __restrict__ w,
    const float* __restrict__ b, const double* __restrict__ ds_in,
    float* __restrict__ out, double* __restrict__ ds_out)
{
    __shared__ float ps[4], pq[4];
    double S = ds_in[0], Q = ds_in[1];
    double mud = S / (double)NC;
    float mu = (float)mud;
    float var = (float)(Q / (double)NC - mud * mud);
    float scale = 1.f / (sqrtf(fmaxf(var, 0.f)) + EPS_LN);
    float s = 0.f, q = 0.f;
    int idx = blockIdx.x * 256 + threadIdx.x;
    int stride = gridDim.x * 256;
    for (int i = idx; i < NC / 4; i += stride) {
        int c = (i & 15) << 2;
        float4 v = reinterpret_cast<const float4*>(in)[i];
        float4 wv = *reinterpret_cast<const float4*>(w + c);
        float4 bv = *reinterpret_cast<const float4*>(b + c);
        float4 o;
        o.x = fmaxf(fmaf((v.x - mu) * scale, wv.x, bv.x), 0.f);
        o.y = fmaxf(fmaf((v.y - mu) * scale, wv.y, bv.y), 0.f);
        o.z = fmaxf(fmaf((v.z - mu) * scale, wv.z, bv.z), 0.f);
        o.w = fmaxf(fmaf((v.w - mu) * scale, wv.w, bv.w), 0.f);
        reinterpret_cast<float4*>(out)[i] = o;
        s += (o.x + o.y) + (o.z + o.w);
        q += fmaf(o.x, o.x, o.y * o.y) + fmaf(o.z, o.z, o.w * o.w);
    }
    int lane = threadIdx.x & 63, wv2 = threadIdx.x >> 6;
    #pragma unroll
    for (int o = 32; o; o >>= 1) { s += __shfl_xor(s, o); q += __shfl_xor(q, o); }
    if (lane == 0) { ps[wv2] = s; pq[wv2] = q; }
    __syncthreads();
    if (threadIdx.x == 0) {
        unsafeAtomicAdd(ds_out + 0, (double)((ps[0] + ps[1]) + (ps[2] + ps[3])));
        unsafeAtomicAdd(ds_out + 1, (double)((pq[0] + pq[1]) + (pq[2] + pq[3])));
    }
}

// ---------------- head: node-per-lane, chunked, no persistent y1 ----------------
__global__ __launch_bounds__(256) void head_kernel(
    const float* __restrict__ xc,
    const float* __restrict__ W1, const float* __restrict__ b1,
    const float* __restrict__ W2, const float* __restrict__ b2,
    const float* __restrict__ W3, const float* __restrict__ b3,
    float* __restrict__ out)
{
    const int lane = threadIdx.x & 63;
    const int tile = blockIdx.x * 4 + (threadIdx.x >> 6);
    if (tile >= NT) return;
    const int base = tile * 64;
    const int node = base + lane;
    const bool act = node < NN;
    const float* xp = xc + (size_t)(act ? node : base) * CH;
    float x[64];
    #pragma unroll
    for (int c4 = 0; c4 < 16; ++c4) {
        float4 v = *reinterpret_cast<const float4*>(xp + c4 * 4);
        x[c4 * 4 + 0] = v.x; x[c4 * 4 + 1] = v.y;
        x[c4 * 4 + 2] = v.z; x[c4 * 4 + 3] = v.w;
    }
    float y2[64];
    #pragma unroll
    for (int c = 0; c < 64; ++c) y2[c] = b2[c];
    for (int jb = 0; jb < 4; ++jb) {            // y1 chunk -> immediately into y2
        float acc[16];
        #pragma unroll
        for (int i = 0; i < 16; ++i) acc[i] = b1[jb * 16 + i];
        #pragma unroll
        for (int c = 0; c < 64; ++c) {
            float xv = x[c];
            #pragma unroll
            for (int i = 0; i < 16; ++i)
                acc[i] = fmaf(xv, W1[c * 64 + jb * 16 + i], acc[i]);
        }
        #pragma unroll
        for (int i = 0; i < 16; ++i) {
            float r = fmaxf(acc[i], 0.f);
            const int j = jb * 16 + i;
            #pragma unroll
            for (int c = 0; c < 64; ++c)
                y2[c] = fmaf(r, W2[j * 64 + c], y2[c]);
        }
    }
    float p0 = b3[0], p1 = b3[1];
    #pragma unroll
    for (int c = 0; c < 64; ++c) {
        float r = fmaxf(y2[c], 0.f);
        p0 = fmaf(r, W3[c * 2 + 0], p0);
        p1 = fmaf(r, W3[c * 2 + 1], p1);
    }
    if (act) {
        float2 st; st.x = p0; st.y = p1;
        *reinterpret_cast<float2*>(out + (size_t)node * 2) = st;
    }
}

extern "C" void kernel_launch(void* const* d_in, const int* in_sizes, int n_in,
                              void* d_out, int out_size, void* d_ws, size_t ws_size,
                              hipStream_t stream)
{
    const float* x     = (const float*)d_in[0];
    const int*   ei    = (const int*)d_in[1];
    const float* c1W1  = (const float*)d_in[2];
    const float* c1b1  = (const float*)d_in[3];
    const float* c1lnw = (const float*)d_in[4];
    const float* c1lnb = (const float*)d_in[5];
    const float* c1W2  = (const float*)d_in[6];
    const float* c1b2  = (const float*)d_in[7];
    const float* n1w   = (const float*)d_in[8];
    const float* n1b   = (const float*)d_in[9];
    const float* cW1   = (const float*)d_in[10];
    const float* cb1   = (const float*)d_in[11];
    const float* clnw  = (const float*)d_in[12];
    const float* clnb  = (const float*)d_in[13];
    const float* cW2   = (const float*)d_in[14];
    const float* cb2   = (const float*)d_in[15];
    const float* nw    = (const float*)d_in[16];
    const float* nb    = (const float*)d_in[17];
    const float* lW1   = (const float*)d_in[18];
    const float* lb1   = (const float*)d_in[19];
    const float* lW2   = (const float*)d_in[20];
    const float* lb2   = (const float*)d_in[21];
    const float* lW3   = (const float*)d_in[22];
    const float* lb3   = (const float*)d_in[23];
    float* out = (float*)d_out;

    // workspace: bufA, bufB, hbuf [N,64]; cursor[NN]; off[NN+2]; esrc[NE]; dsum f64
    float* bufA = (float*)d_ws;
    float* bufB = bufA + NC;
    float* hbuf = bufB + NC;
    int* cursor = (int*)(hbuf + NC);
    int* off    = cursor + NN;
    int* esrc   = off + NN + 2;
    double* dsum = (double*)(esrc + NE);

    hipMemsetAsync(cursor, 0, NN * sizeof(int), stream);
    hipMemsetAsync(dsum, 0, 10 * sizeof(double), stream);
    hist_kernel<<<3125, 256, 0, stream>>>(ei, cursor);
    scan_kernel<<<1, 1024, 0, stream>>>(cursor, off);
    scatter_kernel<<<3125, 256, 0, stream>>>(ei, cursor, esrc);

    const int AGG_BLOCKS = 25000;   // wave per node
    const int MLP_BLOCKS = 391;     // 4 tiles per block

    // layer 1 (plain)
    agg_kernel<0><<<AGG_BLOCKS, 256, 0, stream>>>(x, off, esrc, nullptr, nullptr, nullptr, hbuf);
    mlp_kernel<0><<<MLP_BLOCKS, 256, 0, stream>>>(hbuf, nullptr, c1W1, c1b1, c1lnw, c1lnb,
                                                  c1W2, c1b2, bufA, dsum + 0);
    ln_apply_kernel<<<2048, 256, 0, stream>>>(bufA, n1w, n1b, dsum + 0, bufB, dsum + 2);

    // layers 2..4 (res+), ping-pong xc between bufB/bufA
    agg_kernel<1><<<AGG_BLOCKS, 256, 0, stream>>>(bufB, off, esrc, dsum + 2, nw + 0, nb + 0, hbuf);
    mlp_kernel<1><<<MLP_BLOCKS, 256, 0, stream>>>(hbuf, bufB, cW1 + 0 * 8192, cb1 + 0 * 128,
                                                  clnw + 0 * 128, clnb + 0 * 128,
                                                  cW2 + 0 * 8192, cb2 + 0 * 64, bufA, dsum + 4);

    agg_kernel<1><<<AGG_BLOCKS, 256, 0, stream>>>(bufA, off, esrc, dsum + 4, nw + 64, nb + 64, hbuf);
    mlp_kernel<1><<<MLP_BLOCKS, 256, 0, stream>>>(hbuf, bufA, cW1 + 1 * 8192, cb1 + 1 * 128,
                                                  clnw + 1 * 128, clnb + 1 * 128,
                                                  cW2 + 1 * 8192, cb2 + 1 * 64, bufB, dsum + 6);

    agg_kernel<1><<<AGG_BLOCKS, 256, 0, stream>>>(bufB, off, esrc, dsum + 6, nw + 128, nb + 128, hbuf);
    mlp_kernel<1><<<MLP_BLOCKS, 256, 0, stream>>>(hbuf, bufB, cW1 + 2 * 8192, cb1 + 2 * 128,
                                                  clnw + 2 * 128, clnb + 2 * 128,
                                                  cW2 + 2 * 8192, cb2 + 2 * 64, bufA, dsum + 8);

    // dense head
    head_kernel<<<MLP_BLOCKS, 256, 0, stream>>>(bufA, lW1, lb1, lW2, lb2, lW3, lb3, out);
}